// Round 3
// baseline (998.860 us; speedup 1.0000x reference)
//
#include <hip/hip_runtime.h>
#include <math.h>

typedef __attribute__((ext_vector_type(8))) short s16x8;
typedef __attribute__((ext_vector_type(4))) float f32x4;

__device__ __forceinline__ float b2f(unsigned short u){
  unsigned int i = ((unsigned int)u) << 16;
  float f; __builtin_memcpy(&f, &i, 4); return f;
}
__device__ __forceinline__ unsigned short f2b(float f){
  unsigned int i; __builtin_memcpy(&i, &f, 4);
  unsigned int r = (i + 0x7fffu + ((i >> 16) & 1u)) >> 16;
  return (unsigned short)r;
}
__device__ __forceinline__ f32x4 mfma16(s16x8 a, s16x8 b, f32x4 c){
  return __builtin_amdgcn_mfma_f32_16x16x32_bf16(a, b, c, 0, 0, 0);
}
__device__ __forceinline__ float gelu_exact(float x){
  return 0.5f * x * (1.0f + erff(x * 0.70710678118654752f));
}

// ---------------- transpose + fp32->bf16: out[C][R] = bf16(in[R][C]) ----------------
__global__ void transpose_k(const float* __restrict__ in,
                            unsigned short* __restrict__ out, int R, int C){
  __shared__ unsigned short tile[32][33];
  int c0 = blockIdx.x * 32, r0 = blockIdx.y * 32;
  int tx = threadIdx.x, ty = threadIdx.y;   // block (32,8)
  #pragma unroll
  for(int i = 0; i < 4; i++)
    tile[ty + 8*i][tx] = f2b(in[(size_t)(r0 + ty + 8*i) * C + c0 + tx]);
  __syncthreads();
  #pragma unroll
  for(int i = 0; i < 4; i++)
    out[(size_t)(c0 + ty + 8*i) * R + r0 + tx] = tile[tx][ty + 8*i];
}

// ---------------- LayerNorm over 1024 (fp32 in, bf16 out), one block per row ----------------
__global__ __launch_bounds__(256) void ln_k(const float* __restrict__ x,
                                            const float* __restrict__ g,
                                            const float* __restrict__ b,
                                            unsigned short* __restrict__ out){
  int row = blockIdx.x, t = threadIdx.x;
  const float4* xr = (const float4*)(x + (size_t)row * 1024);
  float4 u = xr[t];
  float s  = u.x + u.y + u.z + u.w;
  float ss = u.x*u.x + u.y*u.y + u.z*u.z + u.w*u.w;
  for(int o = 32; o; o >>= 1){ s += __shfl_down(s, o, 64); ss += __shfl_down(ss, o, 64); }
  __shared__ float red[16];
  int lane = t & 63, wv = t >> 6;
  if(!lane){ red[wv] = s; red[8 + wv] = ss; }
  __syncthreads();
  if(!t){
    float S  = red[0] + red[1] + red[2] + red[3];
    float SS = red[8] + red[9] + red[10] + red[11];
    float m  = S * (1.0f/1024.0f);
    float var = SS * (1.0f/1024.0f) - m*m;
    red[0] = m; red[1] = rsqrtf(var + 1e-5f);
  }
  __syncthreads();
  float m = red[0], inv = red[1];
  float4 ug = ((const float4*)g)[t];
  float4 ub = ((const float4*)b)[t];
  ushort4 o4;
  o4.x = f2b((u.x - m) * inv * ug.x + ub.x);
  o4.y = f2b((u.y - m) * inv * ug.y + ub.y);
  o4.z = f2b((u.z - m) * inv * ug.z + ub.z);
  o4.w = f2b((u.w - m) * inv * ug.w + ub.w);
  ((ushort4*)(out + (size_t)row * 1024))[t] = o4;
}

// ---------------- GEMM: C[M][N] = epi(A[M][K] @ Bt[N][K]^T) ----------------
// A,Bt bf16; C fp32 or bf16 (c_fp32 flag); bias/res fp32; mul bf16.
// 128x128 tile, BK=32, 4 waves each 64x64 (4x4 of 16x16x32 bf16 MFMA)
// NOTE: C / res / mul may alias (per-element same-thread RMW) -> no __restrict__.
__global__ __launch_bounds__(256) void gemm_bt(
    const unsigned short* __restrict__ A, const unsigned short* __restrict__ Bt,
    void* Cv, int N, int K,
    const float* __restrict__ bias, const float* res,
    const unsigned short* mul, int act_gelu, int c_fp32)
{
  __shared__ unsigned short As[128 * 32];
  __shared__ unsigned short Bs[128 * 32];
  const int m0 = blockIdx.y * 128, n0 = blockIdx.x * 128;
  const int tid = threadIdx.x;
  const int wave = tid >> 6, lane = tid & 63;
  const int wm = (wave >> 1) * 64, wn = (wave & 1) * 64;
  const int lrow = lane & 15, lk = (lane >> 4) * 8;
  f32x4 acc[4][4];
  #pragma unroll
  for(int i = 0; i < 4; i++)
    #pragma unroll
    for(int j = 0; j < 4; j++)
      #pragma unroll
      for(int r = 0; r < 4; r++) acc[i][j][r] = 0.0f;

  const int nk = K >> 5;
  for(int kt = 0; kt < nk; kt++){
    const int k0 = kt << 5;
    if(kt) __syncthreads();
    #pragma unroll
    for(int it = 0; it < 2; it++){
      int cc = tid + it * 256;
      int r = cc >> 2, c8 = (cc & 3) * 8;
      *(s16x8*)&As[r*32 + c8] = *(const s16x8*)&A [(size_t)(m0 + r)*K + k0 + c8];
      *(s16x8*)&Bs[r*32 + c8] = *(const s16x8*)&Bt[(size_t)(n0 + r)*K + k0 + c8];
    }
    __syncthreads();
    s16x8 af[4], bfv[4];
    #pragma unroll
    for(int i = 0; i < 4; i++){
      af [i] = *(const s16x8*)&As[(wm + i*16 + lrow)*32 + lk];
      bfv[i] = *(const s16x8*)&Bs[(wn + i*16 + lrow)*32 + lk];
    }
    #pragma unroll
    for(int i = 0; i < 4; i++)
      #pragma unroll
      for(int j = 0; j < 4; j++)
        acc[i][j] = mfma16(af[i], bfv[j], acc[i][j]);
  }
  const int qr = (lane >> 4) * 4;
  #pragma unroll
  for(int i = 0; i < 4; i++){
    #pragma unroll
    for(int j = 0; j < 4; j++){
      int col = n0 + wn + j*16 + lrow;
      float bv = bias ? bias[col] : 0.0f;
      #pragma unroll
      for(int r = 0; r < 4; r++){
        int row = m0 + wm + i*16 + qr + r;
        float v = acc[i][j][r] + bv;
        if(act_gelu) v = gelu_exact(v);
        size_t idx = (size_t)row * N + col;
        if(mul) v *= b2f(mul[idx]);
        if(res) v += res[idx];
        if(c_fp32) ((float*)Cv)[idx] = v;
        else       ((unsigned short*)Cv)[idx] = f2b(v);
      }
    }
  }
}

// ---------------- sliding-window local attention ----------------
// one block per (window n, head h, batch b); 256 threads = 4 waves, wave w owns 32 q rows
// qk: bf16 [16384][2048] = [q | k] per row ; vbuf: bf16 [16384][1024] (scratch in d_out)
__global__ __launch_bounds__(256, 1) void attn_k(const unsigned short* __restrict__ qk,
                                                 const unsigned short* __restrict__ vbuf,
                                                 const float* __restrict__ rel_bias,
                                                 unsigned short* __restrict__ attn_out)
{
  __shared__ unsigned short kvS[128 * 72];   // union: kc half [128][72] / vcT half [64][136]
  __shared__ unsigned short PS[128 * 136];   // P half [128 rows][128 cols padded to 136]
  __shared__ float biasS[256];

  const int n = blockIdx.x, h = blockIdx.y, b = blockIdx.z;
  const int tid = threadIdx.x;
  const int wave = tid >> 6, lane = tid & 63;
  const int lrow = lane & 15, quad = lane >> 4, lk = quad * 8;
  const int rbase = wave * 32;
  const size_t rowbase = (size_t)b * 4096;
  const int prev = (n > 0) ? (n - 1) : 0;   // clamped; masked when n==0

  biasS[tid] = rel_bias[h * 256 + tid];

  // Q fragments straight from global (K-contiguous)
  s16x8 aq[2][2];
  #pragma unroll
  for(int mi = 0; mi < 2; mi++)
    #pragma unroll
    for(int kk = 0; kk < 2; kk++)
      aq[mi][kk] = *(const s16x8*)&qk[(rowbase + n*128 + rbase + mi*16 + lrow)*2048
                                      + h*64 + kk*32 + lk];

  f32x4 lg[2][16];
  #pragma unroll
  for(int mi = 0; mi < 2; mi++)
    #pragma unroll
    for(int nj = 0; nj < 16; nj++)
      #pragma unroll
      for(int r = 0; r < 4; r++) lg[mi][nj][r] = 0.0f;

  // ---- QK^T over kc in two 128-column halves ----
  for(int jh = 0; jh < 2; jh++){
    if(jh) __syncthreads();
    #pragma unroll
    for(int it = 0; it < 4; it++){
      int cid = tid + it * 256;               // 128 rows x 8 chunks
      int jloc = cid >> 3, c8 = (cid & 7) * 8;
      int j = jh * 128 + jloc;
      int srow = (j < 128) ? (prev*128 + j) : (n*128 + j - 128);
      *(s16x8*)&kvS[jloc*72 + c8] =
        *(const s16x8*)&qk[(rowbase + srow)*2048 + 1024 + h*64 + c8];
    }
    __syncthreads();
    #pragma unroll
    for(int njl = 0; njl < 8; njl++){
      #pragma unroll
      for(int kk = 0; kk < 2; kk++){
        s16x8 bk = *(const s16x8*)&kvS[(njl*16 + lrow)*72 + kk*32 + lk];
        #pragma unroll
        for(int mi = 0; mi < 2; mi++)
          lg[mi][jh*8 + njl] = mfma16(aq[mi][kk], bk, lg[mi][jh*8 + njl]);
      }
    }
  }
  __syncthreads();

  // ---- mask + rel_bias + softmax (in registers) ----
  #pragma unroll
  for(int mi = 0; mi < 2; mi++){
    #pragma unroll
    for(int r = 0; r < 4; r++){
      int i = rbase + mi*16 + quad*4 + r;
      float mx = -3e38f;
      #pragma unroll
      for(int nj = 0; nj < 16; nj++){
        int j = nj*16 + lrow;
        int dist = i + 128 - j;
        bool valid = (dist >= 0) && ((n > 0) || (j >= 128));
        float l = valid ? (lg[mi][nj][r] * 0.125f + biasS[dist & 255]) : -1e9f;
        lg[mi][nj][r] = l;
        mx = fmaxf(mx, l);
      }
      #pragma unroll
      for(int o = 1; o < 16; o <<= 1) mx = fmaxf(mx, __shfl_xor(mx, o, 64));
      float s = 0.0f;
      #pragma unroll
      for(int nj = 0; nj < 16; nj++){
        float p = __expf(lg[mi][nj][r] - mx);
        lg[mi][nj][r] = p;
        s += p;
      }
      #pragma unroll
      for(int o = 1; o < 16; o <<= 1) s += __shfl_xor(s, o, 64);
      float inv = 1.0f / s;
      #pragma unroll
      for(int nj = 0; nj < 16; nj++) lg[mi][nj][r] *= inv;
    }
  }

  // ---- P @ vc in two 128-key halves ----
  f32x4 o_acc[2][4];
  #pragma unroll
  for(int mi = 0; mi < 2; mi++)
    #pragma unroll
    for(int nj = 0; nj < 4; nj++)
      #pragma unroll
      for(int r = 0; r < 4; r++) o_acc[mi][nj][r] = 0.0f;

  for(int jh = 0; jh < 2; jh++){
    // stage vc^T half: kvS[d][j] (stride 136), thread t -> column j=t>>1, d-range (t&1)*32..+32
    {
      int jloc = tid >> 1;
      int dbase = (tid & 1) * 32;
      int j = jh * 128 + jloc;
      int srow = (j < 128) ? (prev*128 + j) : (n*128 + j - 128);
      const unsigned short* vr = &vbuf[(rowbase + srow)*1024 + h*64 + dbase];
      #pragma unroll
      for(int i8 = 0; i8 < 4; i8++){
        s16x8 vv = *(const s16x8*)&vr[i8 * 8];
        #pragma unroll
        for(int e = 0; e < 8; e++)
          kvS[(dbase + i8*8 + e)*136 + jloc] = (unsigned short)vv[e];
      }
    }
    // write this half of P (each wave its own 32 rows)
    #pragma unroll
    for(int mi = 0; mi < 2; mi++)
      #pragma unroll
      for(int r = 0; r < 4; r++)
        #pragma unroll
        for(int njl = 0; njl < 8; njl++)
          PS[(rbase + mi*16 + quad*4 + r)*136 + njl*16 + lrow] = f2b(lg[mi][jh*8 + njl][r]);
    __syncthreads();
    #pragma unroll
    for(int kk = 0; kk < 4; kk++){
      s16x8 ap[2];
      #pragma unroll
      for(int mi = 0; mi < 2; mi++)
        ap[mi] = *(const s16x8*)&PS[(rbase + mi*16 + lrow)*136 + kk*32 + lk];
      #pragma unroll
      for(int nj = 0; nj < 4; nj++){
        s16x8 bv = *(const s16x8*)&kvS[(nj*16 + lrow)*136 + kk*32 + lk];
        #pragma unroll
        for(int mi = 0; mi < 2; mi++)
          o_acc[mi][nj] = mfma16(ap[mi], bv, o_acc[mi][nj]);
      }
    }
    __syncthreads();
  }

  // ---- write out: attn_out[b*4096 + n*128 + i][h*64 + d]  (bf16) ----
  #pragma unroll
  for(int mi = 0; mi < 2; mi++)
    #pragma unroll
    for(int nj = 0; nj < 4; nj++)
      #pragma unroll
      for(int r = 0; r < 4; r++){
        size_t row = rowbase + n*128 + rbase + mi*16 + quad*4 + r;
        int col = h*64 + nj*16 + lrow;
        attn_out[row * 1024 + col] = f2b(o_acc[mi][nj][r]);
      }
}

// ---------------- launcher ----------------
extern "C" void kernel_launch(void* const* d_in, const int* in_sizes, int n_in,
                              void* d_out, int out_size, void* d_ws, size_t ws_size,
                              hipStream_t stream) {
  const float* x     = (const float*)d_in[0];
  const float* ln1_g = (const float*)d_in[1];
  const float* ln1_b = (const float*)d_in[2];
  const float* ln2_g = (const float*)d_in[3];
  const float* ln2_b = (const float*)d_in[4];
  const float* wq    = (const float*)d_in[5];
  const float* wk    = (const float*)d_in[6];
  const float* wv    = (const float*)d_in[7];
  const float* wo    = (const float*)d_in[8];
  const float* bo    = (const float*)d_in[9];
  const float* rel   = (const float*)d_in[10];
  const float* wff1  = (const float*)d_in[11];
  const float* bff1  = (const float*)d_in[12];
  const float* wff2  = (const float*)d_in[13];
  const float* bff2  = (const float*)d_in[14];
  float* out = (float*)d_out;
  char*  ws  = (char*)d_ws;

  // ws layout (byte offsets). Peak usage: 121,634,816 bytes = 116 MiB.
  unsigned short* wqkvT = (unsigned short*)(ws);              //  6 MB  [wqT|wkT|wvT] bf16
  unsigned short* woT   = (unsigned short*)(ws +  6291456);   //  2 MB
  unsigned short* wff1T = (unsigned short*)(ws +  8388608);   //  8 MB
  unsigned short* wff2T = (unsigned short*)(ws + 16777216);   //  4 MB
  unsigned short* h     = (unsigned short*)(ws + 20971520);   // 32 MB (ln1/attn_out/ln2, bf16)
  unsigned short* qk    = (unsigned short*)(ws + 54525952);   // 64 MB ([q|k] stride 2048, bf16)
  unsigned short* ff    = qk;                                 // reuses dead qk region (bf16)
  unsigned short* vbuf  = (unsigned short*)d_out;             // V bf16 scratch in d_out (dead until x1)
  float*          x1    = out;                                // x + attn-proj (fp32, in d_out)

  dim3 tb(32, 8);
  transpose_k<<<dim3(32, 32),  tb, 0, stream>>>(wq,   wqkvT,           1024, 1024);
  transpose_k<<<dim3(32, 32),  tb, 0, stream>>>(wk,   wqkvT + 1048576, 1024, 1024);
  transpose_k<<<dim3(32, 32),  tb, 0, stream>>>(wv,   wqkvT + 2097152, 1024, 1024);
  transpose_k<<<dim3(32, 32),  tb, 0, stream>>>(wo,   woT,             1024, 1024);
  transpose_k<<<dim3(128, 32), tb, 0, stream>>>(wff1, wff1T,           1024, 4096);
  transpose_k<<<dim3(32, 64),  tb, 0, stream>>>(wff2, wff2T,           2048, 1024);

  // h = bf16(LN1(x))
  ln_k<<<16384, 256, 0, stream>>>(x, ln1_g, ln1_b, h);
  // qk = h @ [wq|wk]   (N=2048, bf16 out)
  gemm_bt<<<dim3(16, 128), 256, 0, stream>>>(h, wqkvT, qk, 2048, 1024,
                                             nullptr, nullptr, nullptr, 0, 0);
  // vbuf = h @ wv      (N=1024, bf16 out into d_out scratch)
  gemm_bt<<<dim3(8, 128), 256, 0, stream>>>(h, wqkvT + 2097152, vbuf, 1024, 1024,
                                            nullptr, nullptr, nullptr, 0, 0);
  // attention -> h (bf16 attn_out)
  attn_k<<<dim3(32, 16, 4), 256, 0, stream>>>(qk, vbuf, rel, h);
  // x1 = x + attn_out @ wo + bo   (fp32 into d_out; overwrites dead V)
  gemm_bt<<<dim3(8, 128), 256, 0, stream>>>(h, woT, x1, 1024, 1024,
                                            bo, x, nullptr, 0, 1);
  // h = bf16(LN2(x1))
  ln_k<<<16384, 256, 0, stream>>>(x1, ln2_g, ln2_b, h);
  // ff = gelu(h @ w_ff1[:,2048:] + b_ff1[2048:])          (gate, bf16)
  gemm_bt<<<dim3(16, 128), 256, 0, stream>>>(h, wff1T + 2048*1024, ff, 2048, 1024,
                                             bff1 + 2048, nullptr, nullptr, 1, 0);
  // ff = (h @ w_ff1[:,:2048] + b_ff1[:2048]) * ff         (per-element RMW, bf16)
  gemm_bt<<<dim3(16, 128), 256, 0, stream>>>(h, wff1T, ff, 2048, 1024,
                                             bff1, nullptr, ff, 0, 0);
  // out = x1 + ff @ w_ff2 + b_ff2   (fp32, reads res from d_out, writes d_out; same-thread RMW)
  gemm_bt<<<dim3(8, 128), 256, 0, stream>>>(ff, wff2T, out, 1024, 2048,
                                            bff2, x1, nullptr, 0, 1);
}

// Round 4
// 975.267 us; speedup vs baseline: 1.0242x; 1.0242x over previous
//
#include <hip/hip_runtime.h>
#include <math.h>

typedef __attribute__((ext_vector_type(8))) short s16x8;
typedef __attribute__((ext_vector_type(4))) float f32x4;

__device__ __forceinline__ float b2f(unsigned short u){
  unsigned int i = ((unsigned int)u) << 16;
  float f; __builtin_memcpy(&f, &i, 4); return f;
}
__device__ __forceinline__ unsigned short f2b(float f){
  unsigned int i; __builtin_memcpy(&i, &f, 4);
  unsigned int r = (i + 0x7fffu + ((i >> 16) & 1u)) >> 16;
  return (unsigned short)r;
}
__device__ __forceinline__ f32x4 mfma16(s16x8 a, s16x8 b, f32x4 c){
  return __builtin_amdgcn_mfma_f32_16x16x32_bf16(a, b, c, 0, 0, 0);
}
__device__ __forceinline__ float gelu_exact(float x){
  return 0.5f * x * (1.0f + erff(x * 0.70710678118654752f));
}
// async global->LDS, 16 B per lane; lds base must be wave-uniform (m97 pattern)
__device__ __forceinline__ void gl_lds16(const unsigned short* g, unsigned short* l){
  __builtin_amdgcn_global_load_lds(
      (const __attribute__((address_space(1))) unsigned int*)g,
      (__attribute__((address_space(3))) unsigned int*)l, 16, 0, 0);
}

// ---------------- transpose + fp32->bf16: out[C][R] = bf16(in[R][C]) ----------------
__global__ void transpose_k(const float* __restrict__ in,
                            unsigned short* __restrict__ out, int R, int C){
  __shared__ unsigned short tile[32][33];
  int c0 = blockIdx.x * 32, r0 = blockIdx.y * 32;
  int tx = threadIdx.x, ty = threadIdx.y;   // block (32,8)
  #pragma unroll
  for(int i = 0; i < 4; i++)
    tile[ty + 8*i][tx] = f2b(in[(size_t)(r0 + ty + 8*i) * C + c0 + tx]);
  __syncthreads();
  #pragma unroll
  for(int i = 0; i < 4; i++)
    out[(size_t)(c0 + ty + 8*i) * R + r0 + tx] = tile[tx][ty + 8*i];
}

// ---------------- LayerNorm over 1024 (fp32 in, bf16 out), one block per row ----------------
__global__ __launch_bounds__(256) void ln_k(const float* __restrict__ x,
                                            const float* __restrict__ g,
                                            const float* __restrict__ b,
                                            unsigned short* __restrict__ out){
  int row = blockIdx.x, t = threadIdx.x;
  const float4* xr = (const float4*)(x + (size_t)row * 1024);
  float4 u = xr[t];
  float s  = u.x + u.y + u.z + u.w;
  float ss = u.x*u.x + u.y*u.y + u.z*u.z + u.w*u.w;
  for(int o = 32; o; o >>= 1){ s += __shfl_down(s, o, 64); ss += __shfl_down(ss, o, 64); }
  __shared__ float red[16];
  int lane = t & 63, wv = t >> 6;
  if(!lane){ red[wv] = s; red[8 + wv] = ss; }
  __syncthreads();
  if(!t){
    float S  = red[0] + red[1] + red[2] + red[3];
    float SS = red[8] + red[9] + red[10] + red[11];
    float m  = S * (1.0f/1024.0f);
    float var = SS * (1.0f/1024.0f) - m*m;
    red[0] = m; red[1] = rsqrtf(var + 1e-5f);
  }
  __syncthreads();
  float m = red[0], inv = red[1];
  float4 ug = ((const float4*)g)[t];
  float4 ub = ((const float4*)b)[t];
  ushort4 o4;
  o4.x = f2b((u.x - m) * inv * ug.x + ub.x);
  o4.y = f2b((u.y - m) * inv * ug.y + ub.y);
  o4.z = f2b((u.z - m) * inv * ug.z + ub.z);
  o4.w = f2b((u.w - m) * inv * ug.w + ub.w);
  ((ushort4*)(out + (size_t)row * 1024))[t] = o4;
}

// ---------------- GEMM: C[M][N] = epi(A[M][K] @ Bt[N][K]^T) ----------------
// m97 structure: 128x128 tile, BK=32, global_load_lds width-16 staging.
// A,Bt bf16; C fp32 or bf16 (c_fp32); bias/res fp32; mul bf16.
// XCD swizzle: all n-tiles of one m-tile share lin%8 -> same XCD L2 (A fetched once/XCD).
// NOTE: C / res / mul may alias (per-element same-thread RMW) -> no __restrict__.
__global__ __launch_bounds__(256) void gemm_bt(
    const unsigned short* __restrict__ A, const unsigned short* __restrict__ Bt,
    void* Cv, int N, int K,
    const float* __restrict__ bias, const float* res,
    const unsigned short* mul, int act_gelu, int c_fp32)
{
  __shared__ __align__(16) unsigned short As[128 * 32];
  __shared__ __align__(16) unsigned short Bs[128 * 32];

  int m_tile, n_tile;
  {
    unsigned int lin = blockIdx.y * gridDim.x + blockIdx.x;
    unsigned int mt = gridDim.y;
    if((mt & 7u) == 0u){
      unsigned int xcd = lin & 7u, idx = lin >> 3, mpx = mt >> 3;
      m_tile = xcd * mpx + (idx % mpx);
      n_tile = idx / mpx;
    } else { m_tile = blockIdx.y; n_tile = blockIdx.x; }
  }
  const int m0 = m_tile * 128, n0 = n_tile * 128;
  const int tid = threadIdx.x;
  const int wave = tid >> 6, lane = tid & 63;
  const int wm = (wave >> 1) * 64, wn = (wave & 1) * 64;
  const int lrow = lane & 15, lk = (lane >> 4) * 8;

  // staging coords: chunk c = i*256+tid covers 8 elems; row=c>>2, col=(c&3)*8.
  // LDS dest (wave-uniform base): elem offset i*2048 + wave*512 (+lane*8 implicit).
  const int sr0 = tid >> 2, sc0 = (tid & 3) * 8;          // i=0 chunk
  const int sr1 = (tid + 256) >> 2, sc1 = sc0;            // i=1 chunk (c&3 unchanged)

  f32x4 acc[4][4];
  #pragma unroll
  for(int i = 0; i < 4; i++)
    #pragma unroll
    for(int j = 0; j < 4; j++)
      #pragma unroll
      for(int r = 0; r < 4; r++) acc[i][j][r] = 0.0f;

  const int nk = K >> 5;
  for(int kt = 0; kt < nk; kt++){
    const int k0 = kt << 5;
    if(kt) __syncthreads();
    gl_lds16(&A [(size_t)(m0 + sr0)*K + k0 + sc0], &As[wave*512]);
    gl_lds16(&Bt[(size_t)(n0 + sr0)*K + k0 + sc0], &Bs[wave*512]);
    gl_lds16(&A [(size_t)(m0 + sr1)*K + k0 + sc1], &As[2048 + wave*512]);
    gl_lds16(&Bt[(size_t)(n0 + sr1)*K + k0 + sc1], &Bs[2048 + wave*512]);
    __syncthreads();   // compiler emits s_waitcnt vmcnt(0) before s_barrier -> staging complete
    s16x8 af[4], bfv[4];
    #pragma unroll
    for(int i = 0; i < 4; i++){
      af [i] = *(const s16x8*)&As[(wm + i*16 + lrow)*32 + lk];
      bfv[i] = *(const s16x8*)&Bs[(wn + i*16 + lrow)*32 + lk];
    }
    #pragma unroll
    for(int i = 0; i < 4; i++)
      #pragma unroll
      for(int j = 0; j < 4; j++)
        acc[i][j] = mfma16(af[i], bfv[j], acc[i][j]);
  }
  const int qr = (lane >> 4) * 4;
  #pragma unroll
  for(int i = 0; i < 4; i++){
    #pragma unroll
    for(int j = 0; j < 4; j++){
      int col = n0 + wn + j*16 + lrow;
      float bv = bias ? bias[col] : 0.0f;
      #pragma unroll
      for(int r = 0; r < 4; r++){
        int row = m0 + wm + i*16 + qr + r;
        float v = acc[i][j][r] + bv;
        if(act_gelu) v = gelu_exact(v);
        size_t idx = (size_t)row * N + col;
        if(mul) v *= b2f(mul[idx]);
        if(res) v += res[idx];
        if(c_fp32) ((float*)Cv)[idx] = v;
        else       ((unsigned short*)Cv)[idx] = f2b(v);
      }
    }
  }
}

// ---------------- sliding-window local attention ----------------
// one block per (window n, head h, batch b); 256 threads = 4 waves, wave w owns 32 q rows
// qk: bf16 [16384][2048] = [q | k] per row ; vbuf: bf16 [16384][1024] (scratch in d_out)
__global__ __launch_bounds__(256, 1) void attn_k(const unsigned short* __restrict__ qk,
                                                 const unsigned short* __restrict__ vbuf,
                                                 const float* __restrict__ rel_bias,
                                                 unsigned short* __restrict__ attn_out)
{
  __shared__ unsigned short kvS[128 * 72];   // union: kc half [128][72] / vcT half [64][136]
  __shared__ unsigned short PS[128 * 136];   // P half [128 rows][128 cols padded to 136]
  __shared__ float biasS[256];

  const int n = blockIdx.x, h = blockIdx.y, b = blockIdx.z;
  const int tid = threadIdx.x;
  const int wave = tid >> 6, lane = tid & 63;
  const int lrow = lane & 15, quad = lane >> 4, lk = quad * 8;
  const int rbase = wave * 32;
  const size_t rowbase = (size_t)b * 4096;
  const int prev = (n > 0) ? (n - 1) : 0;   // clamped; masked when n==0

  biasS[tid] = rel_bias[h * 256 + tid];

  // Q fragments straight from global (K-contiguous)
  s16x8 aq[2][2];
  #pragma unroll
  for(int mi = 0; mi < 2; mi++)
    #pragma unroll
    for(int kk = 0; kk < 2; kk++)
      aq[mi][kk] = *(const s16x8*)&qk[(rowbase + n*128 + rbase + mi*16 + lrow)*2048
                                      + h*64 + kk*32 + lk];

  f32x4 lg[2][16];
  #pragma unroll
  for(int mi = 0; mi < 2; mi++)
    #pragma unroll
    for(int nj = 0; nj < 16; nj++)
      #pragma unroll
      for(int r = 0; r < 4; r++) lg[mi][nj][r] = 0.0f;

  // ---- QK^T over kc in two 128-column halves ----
  for(int jh = 0; jh < 2; jh++){
    if(jh) __syncthreads();
    #pragma unroll
    for(int it = 0; it < 4; it++){
      int cid = tid + it * 256;               // 128 rows x 8 chunks
      int jloc = cid >> 3, c8 = (cid & 7) * 8;
      int j = jh * 128 + jloc;
      int srow = (j < 128) ? (prev*128 + j) : (n*128 + j - 128);
      *(s16x8*)&kvS[jloc*72 + c8] =
        *(const s16x8*)&qk[(rowbase + srow)*2048 + 1024 + h*64 + c8];
    }
    __syncthreads();
    #pragma unroll
    for(int njl = 0; njl < 8; njl++){
      #pragma unroll
      for(int kk = 0; kk < 2; kk++){
        s16x8 bk = *(const s16x8*)&kvS[(njl*16 + lrow)*72 + kk*32 + lk];
        #pragma unroll
        for(int mi = 0; mi < 2; mi++)
          lg[mi][jh*8 + njl] = mfma16(aq[mi][kk], bk, lg[mi][jh*8 + njl]);
      }
    }
  }
  __syncthreads();

  // ---- mask + rel_bias + softmax (in registers) ----
  #pragma unroll
  for(int mi = 0; mi < 2; mi++){
    #pragma unroll
    for(int r = 0; r < 4; r++){
      int i = rbase + mi*16 + quad*4 + r;
      float mx = -3e38f;
      #pragma unroll
      for(int nj = 0; nj < 16; nj++){
        int j = nj*16 + lrow;
        int dist = i + 128 - j;
        bool valid = (dist >= 0) && ((n > 0) || (j >= 128));
        float l = valid ? (lg[mi][nj][r] * 0.125f + biasS[dist & 255]) : -1e9f;
        lg[mi][nj][r] = l;
        mx = fmaxf(mx, l);
      }
      #pragma unroll
      for(int o = 1; o < 16; o <<= 1) mx = fmaxf(mx, __shfl_xor(mx, o, 64));
      float s = 0.0f;
      #pragma unroll
      for(int nj = 0; nj < 16; nj++){
        float p = __expf(lg[mi][nj][r] - mx);
        lg[mi][nj][r] = p;
        s += p;
      }
      #pragma unroll
      for(int o = 1; o < 16; o <<= 1) s += __shfl_xor(s, o, 64);
      float inv = 1.0f / s;
      #pragma unroll
      for(int nj = 0; nj < 16; nj++) lg[mi][nj][r] *= inv;
    }
  }

  // ---- P @ vc in two 128-key halves ----
  f32x4 o_acc[2][4];
  #pragma unroll
  for(int mi = 0; mi < 2; mi++)
    #pragma unroll
    for(int nj = 0; nj < 4; nj++)
      #pragma unroll
      for(int r = 0; r < 4; r++) o_acc[mi][nj][r] = 0.0f;

  for(int jh = 0; jh < 2; jh++){
    // stage vc^T half: kvS[d][j] (stride 136), thread t -> column j=t>>1, d-range (t&1)*32..+32
    {
      int jloc = tid >> 1;
      int dbase = (tid & 1) * 32;
      int j = jh * 128 + jloc;
      int srow = (j < 128) ? (prev*128 + j) : (n*128 + j - 128);
      const unsigned short* vr = &vbuf[(rowbase + srow)*1024 + h*64 + dbase];
      #pragma unroll
      for(int i8 = 0; i8 < 4; i8++){
        s16x8 vv = *(const s16x8*)&vr[i8 * 8];
        #pragma unroll
        for(int e = 0; e < 8; e++)
          kvS[(dbase + i8*8 + e)*136 + jloc] = (unsigned short)vv[e];
      }
    }
    // write this half of P (each wave its own 32 rows)
    #pragma unroll
    for(int mi = 0; mi < 2; mi++)
      #pragma unroll
      for(int r = 0; r < 4; r++)
        #pragma unroll
        for(int njl = 0; njl < 8; njl++)
          PS[(rbase + mi*16 + quad*4 + r)*136 + njl*16 + lrow] = f2b(lg[mi][jh*8 + njl][r]);
    __syncthreads();
    #pragma unroll
    for(int kk = 0; kk < 4; kk++){
      s16x8 ap[2];
      #pragma unroll
      for(int mi = 0; mi < 2; mi++)
        ap[mi] = *(const s16x8*)&PS[(rbase + mi*16 + lrow)*136 + kk*32 + lk];
      #pragma unroll
      for(int nj = 0; nj < 4; nj++){
        s16x8 bv = *(const s16x8*)&kvS[(nj*16 + lrow)*136 + kk*32 + lk];
        #pragma unroll
        for(int mi = 0; mi < 2; mi++)
          o_acc[mi][nj] = mfma16(ap[mi], bv, o_acc[mi][nj]);
      }
    }
    __syncthreads();
  }

  // ---- write out: attn_out[b*4096 + n*128 + i][h*64 + d]  (bf16) ----
  #pragma unroll
  for(int mi = 0; mi < 2; mi++)
    #pragma unroll
    for(int nj = 0; nj < 4; nj++)
      #pragma unroll
      for(int r = 0; r < 4; r++){
        size_t row = rowbase + n*128 + rbase + mi*16 + quad*4 + r;
        int col = h*64 + nj*16 + lrow;
        attn_out[row * 1024 + col] = f2b(o_acc[mi][nj][r]);
      }
}

// ---------------- launcher ----------------
extern "C" void kernel_launch(void* const* d_in, const int* in_sizes, int n_in,
                              void* d_out, int out_size, void* d_ws, size_t ws_size,
                              hipStream_t stream) {
  const float* x     = (const float*)d_in[0];
  const float* ln1_g = (const float*)d_in[1];
  const float* ln1_b = (const float*)d_in[2];
  const float* ln2_g = (const float*)d_in[3];
  const float* ln2_b = (const float*)d_in[4];
  const float* wq    = (const float*)d_in[5];
  const float* wk    = (const float*)d_in[6];
  const float* wv    = (const float*)d_in[7];
  const float* wo    = (const float*)d_in[8];
  const float* bo    = (const float*)d_in[9];
  const float* rel   = (const float*)d_in[10];
  const float* wff1  = (const float*)d_in[11];
  const float* bff1  = (const float*)d_in[12];
  const float* wff2  = (const float*)d_in[13];
  const float* bff2  = (const float*)d_in[14];
  float* out = (float*)d_out;
  char*  ws  = (char*)d_ws;

  // ws layout (byte offsets). Peak usage: 121,634,816 bytes = 116 MiB.
  unsigned short* wqkvT = (unsigned short*)(ws);              //  6 MB  [wqT|wkT|wvT] bf16
  unsigned short* woT   = (unsigned short*)(ws +  6291456);   //  2 MB
  unsigned short* wff1T = (unsigned short*)(ws +  8388608);   //  8 MB
  unsigned short* wff2T = (unsigned short*)(ws + 16777216);   //  4 MB
  unsigned short* h     = (unsigned short*)(ws + 20971520);   // 32 MB (ln1/attn_out/ln2, bf16)
  unsigned short* qk    = (unsigned short*)(ws + 54525952);   // 64 MB ([q|k] stride 2048, bf16)
  unsigned short* ff    = qk;                                 // reuses dead qk region (bf16)
  unsigned short* vbuf  = (unsigned short*)d_out;             // V bf16 scratch in d_out (dead until x1)
  float*          x1    = out;                                // x + attn-proj (fp32, in d_out)

  dim3 tb(32, 8);
  transpose_k<<<dim3(32, 32),  tb, 0, stream>>>(wq,   wqkvT,           1024, 1024);
  transpose_k<<<dim3(32, 32),  tb, 0, stream>>>(wk,   wqkvT + 1048576, 1024, 1024);
  transpose_k<<<dim3(32, 32),  tb, 0, stream>>>(wv,   wqkvT + 2097152, 1024, 1024);
  transpose_k<<<dim3(32, 32),  tb, 0, stream>>>(wo,   woT,             1024, 1024);
  transpose_k<<<dim3(128, 32), tb, 0, stream>>>(wff1, wff1T,           1024, 4096);
  transpose_k<<<dim3(32, 64),  tb, 0, stream>>>(wff2, wff2T,           2048, 1024);

  // h = bf16(LN1(x))
  ln_k<<<16384, 256, 0, stream>>>(x, ln1_g, ln1_b, h);
  // qk = h @ [wq|wk]   (N=2048, bf16 out)
  gemm_bt<<<dim3(16, 128), 256, 0, stream>>>(h, wqkvT, qk, 2048, 1024,
                                             nullptr, nullptr, nullptr, 0, 0);
  // vbuf = h @ wv      (N=1024, bf16 out into d_out scratch)
  gemm_bt<<<dim3(8, 128), 256, 0, stream>>>(h, wqkvT + 2097152, vbuf, 1024, 1024,
                                            nullptr, nullptr, nullptr, 0, 0);
  // attention -> h (bf16 attn_out)
  attn_k<<<dim3(32, 16, 4), 256, 0, stream>>>(qk, vbuf, rel, h);
  // x1 = x + attn_out @ wo + bo   (fp32 into d_out; overwrites dead V)
  gemm_bt<<<dim3(8, 128), 256, 0, stream>>>(h, woT, x1, 1024, 1024,
                                            bo, x, nullptr, 0, 1);
  // h = bf16(LN2(x1))
  ln_k<<<16384, 256, 0, stream>>>(x1, ln2_g, ln2_b, h);
  // ff = gelu(h @ w_ff1[:,2048:] + b_ff1[2048:])          (gate, bf16)
  gemm_bt<<<dim3(16, 128), 256, 0, stream>>>(h, wff1T + 2048*1024, ff, 2048, 1024,
                                             bff1 + 2048, nullptr, nullptr, 1, 0);
  // ff = (h @ w_ff1[:,:2048] + b_ff1[:2048]) * ff         (per-element RMW, bf16)
  gemm_bt<<<dim3(16, 128), 256, 0, stream>>>(h, wff1T, ff, 2048, 1024,
                                             bff1, nullptr, ff, 0, 0);
  // out = x1 + ff @ w_ff2 + b_ff2   (fp32, reads res from d_out, writes d_out; same-thread RMW)
  gemm_bt<<<dim3(8, 128), 256, 0, stream>>>(ff, wff2T, out, 1024, 2048,
                                            bff2, x1, nullptr, 0, 1);
}

// Round 5
// 893.984 us; speedup vs baseline: 1.1173x; 1.0909x over previous
//
#include <hip/hip_runtime.h>
#include <math.h>

typedef __attribute__((ext_vector_type(8))) short s16x8;
typedef __attribute__((ext_vector_type(4))) float f32x4;

__device__ __forceinline__ float b2f(unsigned short u){
  unsigned int i = ((unsigned int)u) << 16;
  float f; __builtin_memcpy(&f, &i, 4); return f;
}
__device__ __forceinline__ unsigned short f2b(float f){
  unsigned int i; __builtin_memcpy(&i, &f, 4);
  unsigned int r = (i + 0x7fffu + ((i >> 16) & 1u)) >> 16;
  return (unsigned short)r;
}
__device__ __forceinline__ f32x4 mfma16(s16x8 a, s16x8 b, f32x4 c){
  return __builtin_amdgcn_mfma_f32_16x16x32_bf16(a, b, c, 0, 0, 0);
}
__device__ __forceinline__ float gelu_exact(float x){
  return 0.5f * x * (1.0f + erff(x * 0.70710678118654752f));
}
// async global->LDS, 16 B per lane; lds base must be wave-uniform (m97 pattern)
__device__ __forceinline__ void gl_lds16(const unsigned short* g, unsigned short* l){
  __builtin_amdgcn_global_load_lds(
      (const __attribute__((address_space(1))) unsigned int*)g,
      (__attribute__((address_space(3))) unsigned int*)l, 16, 0, 0);
}

// ---------------- transpose + fp32->bf16: out[C][R] = bf16(in[R][C]) ----------------
__global__ void transpose_k(const float* __restrict__ in,
                            unsigned short* __restrict__ out, int R, int C){
  __shared__ unsigned short tile[32][33];
  int c0 = blockIdx.x * 32, r0 = blockIdx.y * 32;
  int tx = threadIdx.x, ty = threadIdx.y;   // block (32,8)
  #pragma unroll
  for(int i = 0; i < 4; i++)
    tile[ty + 8*i][tx] = f2b(in[(size_t)(r0 + ty + 8*i) * C + c0 + tx]);
  __syncthreads();
  #pragma unroll
  for(int i = 0; i < 4; i++)
    out[(size_t)(c0 + ty + 8*i) * R + r0 + tx] = tile[tx][ty + 8*i];
}

// ---------------- LayerNorm over 1024 (fp32 in, bf16 out), one block per row ----------------
__global__ __launch_bounds__(256) void ln_k(const float* __restrict__ x,
                                            const float* __restrict__ g,
                                            const float* __restrict__ b,
                                            unsigned short* __restrict__ out){
  int row = blockIdx.x, t = threadIdx.x;
  const float4* xr = (const float4*)(x + (size_t)row * 1024);
  float4 u = xr[t];
  float s  = u.x + u.y + u.z + u.w;
  float ss = u.x*u.x + u.y*u.y + u.z*u.z + u.w*u.w;
  for(int o = 32; o; o >>= 1){ s += __shfl_down(s, o, 64); ss += __shfl_down(ss, o, 64); }
  __shared__ float red[16];
  int lane = t & 63, wv = t >> 6;
  if(!lane){ red[wv] = s; red[8 + wv] = ss; }
  __syncthreads();
  if(!t){
    float S  = red[0] + red[1] + red[2] + red[3];
    float SS = red[8] + red[9] + red[10] + red[11];
    float m  = S * (1.0f/1024.0f);
    float var = SS * (1.0f/1024.0f) - m*m;
    red[0] = m; red[1] = rsqrtf(var + 1e-5f);
  }
  __syncthreads();
  float m = red[0], inv = red[1];
  float4 ug = ((const float4*)g)[t];
  float4 ub = ((const float4*)b)[t];
  ushort4 o4;
  o4.x = f2b((u.x - m) * inv * ug.x + ub.x);
  o4.y = f2b((u.y - m) * inv * ug.y + ub.y);
  o4.z = f2b((u.z - m) * inv * ug.z + ub.z);
  o4.w = f2b((u.w - m) * inv * ug.w + ub.w);
  ((ushort4*)(out + (size_t)row * 1024))[t] = o4;
}

// ---------------- GEMM: C[M][N] = epi(A[M][K] @ Bt[N][K]^T) ----------------
// 128x128 tile, BK=64, global_load_lds width-16, XOR-swizzled k-groups (conflict-free b128 reads).
// Output split: cols [0,n_split) -> Cv (stride n_split); cols [n_split,N) -> Cv2 (stride N-n_split).
// A,Bt bf16; Cv fp32 or bf16 (c_fp32); bias/res fp32; mul bf16.
// XCD swizzle: all n-tiles of one m-tile share lin%8 -> same XCD L2.
// NOTE: Cv / res / mul may alias (per-element same-thread RMW) -> no __restrict__.
__global__ __launch_bounds__(256) void gemm_bt(
    const unsigned short* __restrict__ A, const unsigned short* __restrict__ Bt,
    void* Cv, void* Cv2, int N, int n_split, int K,
    const float* __restrict__ bias, const float* res,
    const unsigned short* mul, int act_gelu, int c_fp32)
{
  __shared__ __align__(16) unsigned short As[128 * 64];
  __shared__ __align__(16) unsigned short Bs[128 * 64];

  int m_tile, n_tile;
  {
    unsigned int lin = blockIdx.y * gridDim.x + blockIdx.x;
    unsigned int mt = gridDim.y;
    if((mt & 7u) == 0u){
      unsigned int xcd = lin & 7u, idx = lin >> 3, mpx = mt >> 3;
      m_tile = xcd * mpx + (idx % mpx);
      n_tile = idx / mpx;
    } else { m_tile = blockIdx.y; n_tile = blockIdx.x; }
  }
  const int m0 = m_tile * 128, n0 = n_tile * 128;
  const int tid = threadIdx.x;
  const int wave = tid >> 6, lane = tid & 63;
  const int wm = (wave >> 1) * 64, wn = (wave & 1) * 64;
  const int lrow = lane & 15, quad = lane >> 4;

  // staging: chunk c = i*256 + tid (i=0..3) -> row = c>>3 = i*32 + (tid>>3),
  // k-group j = c&7 holds swizzled global group cg = j ^ (row&7); LDS offset c*8 elems.
  const int tr  = tid >> 3;                       // row within 32-row slab
  const int scg = ((tid & 7) ^ (tr & 7)) * 8;     // swizzled global col (elems)
  const int xw  = lrow & 7;                       // reader xor term base

  f32x4 acc[4][4];
  #pragma unroll
  for(int i = 0; i < 4; i++)
    #pragma unroll
    for(int j = 0; j < 4; j++)
      #pragma unroll
      for(int r = 0; r < 4; r++) acc[i][j][r] = 0.0f;

  const int nk = K >> 6;
  for(int kt = 0; kt < nk; kt++){
    const int k0 = kt << 6;
    if(kt) __syncthreads();
    #pragma unroll
    for(int i = 0; i < 4; i++){
      int row = i*32 + tr;
      gl_lds16(&A [(size_t)(m0 + row)*K + k0 + scg], &As[i*2048 + wave*512]);
      gl_lds16(&Bt[(size_t)(n0 + row)*K + k0 + scg], &Bs[i*2048 + wave*512]);
    }
    __syncthreads();   // vmcnt(0) drain before barrier -> staging complete
    #pragma unroll
    for(int kk = 0; kk < 2; kk++){
      s16x8 af[4], bfv[4];
      #pragma unroll
      for(int i = 0; i < 4; i++){
        int ga = ((kk<<2) + quad) ^ xw;   // swizzled group
        af [i] = *(const s16x8*)&As[(wm + i*16 + lrow)*64 + ga*8];
        bfv[i] = *(const s16x8*)&Bs[(wn + i*16 + lrow)*64 + ga*8];
      }
      #pragma unroll
      for(int i = 0; i < 4; i++)
        #pragma unroll
        for(int j = 0; j < 4; j++)
          acc[i][j] = mfma16(af[i], bfv[j], acc[i][j]);
    }
  }
  const int qr = quad * 4;
  #pragma unroll
  for(int i = 0; i < 4; i++){
    #pragma unroll
    for(int j = 0; j < 4; j++){
      int col = n0 + wn + j*16 + lrow;
      float bv = bias ? bias[col] : 0.0f;
      #pragma unroll
      for(int r = 0; r < 4; r++){
        int row = m0 + wm + i*16 + qr + r;
        float v = acc[i][j][r] + bv;
        if(act_gelu) v = gelu_exact(v);
        if(col < n_split){
          size_t idx = (size_t)row * n_split + col;
          if(mul) v *= b2f(mul[idx]);
          if(res) v += res[idx];
          if(c_fp32) ((float*)Cv)[idx] = v;
          else       ((unsigned short*)Cv)[idx] = f2b(v);
        } else {
          size_t idx = (size_t)row * (N - n_split) + (col - n_split);
          ((unsigned short*)Cv2)[idx] = f2b(v);
        }
      }
    }
  }
}

// ---------------- sliding-window local attention ----------------
// one block per (window n, head h, batch b); 256 threads = 4 waves, wave w owns 32 q rows
// qk: bf16 [16384][2048] = [q | k] per row ; vbuf: bf16 [16384][1024] (scratch in d_out)
__global__ __launch_bounds__(256, 1) void attn_k(const unsigned short* __restrict__ qk,
                                                 const unsigned short* __restrict__ vbuf,
                                                 const float* __restrict__ rel_bias,
                                                 unsigned short* __restrict__ attn_out)
{
  __shared__ unsigned short kvS[128 * 72];   // union: kc half [128][72] / vcT half [64][136]
  __shared__ unsigned short PS[128 * 136];   // P half [128 rows][128 cols padded to 136]
  __shared__ float biasS[256];

  const int n = blockIdx.x, h = blockIdx.y, b = blockIdx.z;
  const int tid = threadIdx.x;
  const int wave = tid >> 6, lane = tid & 63;
  const int lrow = lane & 15, quad = lane >> 4, lk = quad * 8;
  const int rbase = wave * 32;
  const size_t rowbase = (size_t)b * 4096;
  const int prev = (n > 0) ? (n - 1) : 0;   // clamped; masked when n==0

  biasS[tid] = rel_bias[h * 256 + tid];

  // Q fragments straight from global (K-contiguous)
  s16x8 aq[2][2];
  #pragma unroll
  for(int mi = 0; mi < 2; mi++)
    #pragma unroll
    for(int kk = 0; kk < 2; kk++)
      aq[mi][kk] = *(const s16x8*)&qk[(rowbase + n*128 + rbase + mi*16 + lrow)*2048
                                      + h*64 + kk*32 + lk];

  f32x4 lg[2][16];
  #pragma unroll
  for(int mi = 0; mi < 2; mi++)
    #pragma unroll
    for(int nj = 0; nj < 16; nj++)
      #pragma unroll
      for(int r = 0; r < 4; r++) lg[mi][nj][r] = 0.0f;

  // ---- QK^T over kc in two 128-column halves ----
  for(int jh = 0; jh < 2; jh++){
    if(jh) __syncthreads();
    #pragma unroll
    for(int it = 0; it < 4; it++){
      int cid = tid + it * 256;               // 128 rows x 8 chunks
      int jloc = cid >> 3, c8 = (cid & 7) * 8;
      int j = jh * 128 + jloc;
      int srow = (j < 128) ? (prev*128 + j) : (n*128 + j - 128);
      *(s16x8*)&kvS[jloc*72 + c8] =
        *(const s16x8*)&qk[(rowbase + srow)*2048 + 1024 + h*64 + c8];
    }
    __syncthreads();
    #pragma unroll
    for(int njl = 0; njl < 8; njl++){
      #pragma unroll
      for(int kk = 0; kk < 2; kk++){
        s16x8 bk = *(const s16x8*)&kvS[(njl*16 + lrow)*72 + kk*32 + lk];
        #pragma unroll
        for(int mi = 0; mi < 2; mi++)
          lg[mi][jh*8 + njl] = mfma16(aq[mi][kk], bk, lg[mi][jh*8 + njl]);
      }
    }
  }
  __syncthreads();

  // ---- mask + rel_bias + softmax (in registers) ----
  #pragma unroll
  for(int mi = 0; mi < 2; mi++){
    #pragma unroll
    for(int r = 0; r < 4; r++){
      int i = rbase + mi*16 + quad*4 + r;
      float mx = -3e38f;
      #pragma unroll
      for(int nj = 0; nj < 16; nj++){
        int j = nj*16 + lrow;
        int dist = i + 128 - j;
        bool valid = (dist >= 0) && ((n > 0) || (j >= 128));
        float l = valid ? (lg[mi][nj][r] * 0.125f + biasS[dist & 255]) : -1e9f;
        lg[mi][nj][r] = l;
        mx = fmaxf(mx, l);
      }
      #pragma unroll
      for(int o = 1; o < 16; o <<= 1) mx = fmaxf(mx, __shfl_xor(mx, o, 64));
      float s = 0.0f;
      #pragma unroll
      for(int nj = 0; nj < 16; nj++){
        float p = __expf(lg[mi][nj][r] - mx);
        lg[mi][nj][r] = p;
        s += p;
      }
      #pragma unroll
      for(int o = 1; o < 16; o <<= 1) s += __shfl_xor(s, o, 64);
      float inv = 1.0f / s;
      #pragma unroll
      for(int nj = 0; nj < 16; nj++) lg[mi][nj][r] *= inv;
    }
  }

  // ---- P @ vc in two 128-key halves ----
  f32x4 o_acc[2][4];
  #pragma unroll
  for(int mi = 0; mi < 2; mi++)
    #pragma unroll
    for(int nj = 0; nj < 4; nj++)
      #pragma unroll
      for(int r = 0; r < 4; r++) o_acc[mi][nj][r] = 0.0f;

  for(int jh = 0; jh < 2; jh++){
    // stage vc^T half: kvS[d][j] (stride 136), thread t -> column j=t>>1, d-range (t&1)*32..+32
    {
      int jloc = tid >> 1;
      int dbase = (tid & 1) * 32;
      int j = jh * 128 + jloc;
      int srow = (j < 128) ? (prev*128 + j) : (n*128 + j - 128);
      const unsigned short* vr = &vbuf[(rowbase + srow)*1024 + h*64 + dbase];
      #pragma unroll
      for(int i8 = 0; i8 < 4; i8++){
        s16x8 vv = *(const s16x8*)&vr[i8 * 8];
        #pragma unroll
        for(int e = 0; e < 8; e++)
          kvS[(dbase + i8*8 + e)*136 + jloc] = (unsigned short)vv[e];
      }
    }
    // write this half of P (each wave its own 32 rows)
    #pragma unroll
    for(int mi = 0; mi < 2; mi++)
      #pragma unroll
      for(int r = 0; r < 4; r++)
        #pragma unroll
        for(int njl = 0; njl < 8; njl++)
          PS[(rbase + mi*16 + quad*4 + r)*136 + njl*16 + lrow] = f2b(lg[mi][jh*8 + njl][r]);
    __syncthreads();
    #pragma unroll
    for(int kk = 0; kk < 4; kk++){
      s16x8 ap[2];
      #pragma unroll
      for(int mi = 0; mi < 2; mi++)
        ap[mi] = *(const s16x8*)&PS[(rbase + mi*16 + lrow)*136 + kk*32 + lk];
      #pragma unroll
      for(int nj = 0; nj < 4; nj++){
        s16x8 bv = *(const s16x8*)&kvS[(nj*16 + lrow)*136 + kk*32 + lk];
        #pragma unroll
        for(int mi = 0; mi < 2; mi++)
          o_acc[mi][nj] = mfma16(ap[mi], bv, o_acc[mi][nj]);
      }
    }
    __syncthreads();
  }

  // ---- write out: attn_out[b*4096 + n*128 + i][h*64 + d]  (bf16) ----
  #pragma unroll
  for(int mi = 0; mi < 2; mi++)
    #pragma unroll
    for(int nj = 0; nj < 4; nj++)
      #pragma unroll
      for(int r = 0; r < 4; r++){
        size_t row = rowbase + n*128 + rbase + mi*16 + quad*4 + r;
        int col = h*64 + nj*16 + lrow;
        attn_out[row * 1024 + col] = f2b(o_acc[mi][nj][r]);
      }
}

// ---------------- launcher ----------------
extern "C" void kernel_launch(void* const* d_in, const int* in_sizes, int n_in,
                              void* d_out, int out_size, void* d_ws, size_t ws_size,
                              hipStream_t stream) {
  const float* x     = (const float*)d_in[0];
  const float* ln1_g = (const float*)d_in[1];
  const float* ln1_b = (const float*)d_in[2];
  const float* ln2_g = (const float*)d_in[3];
  const float* ln2_b = (const float*)d_in[4];
  const float* wq    = (const float*)d_in[5];
  const float* wk    = (const float*)d_in[6];
  const float* wv    = (const float*)d_in[7];
  const float* wo    = (const float*)d_in[8];
  const float* bo    = (const float*)d_in[9];
  const float* rel   = (const float*)d_in[10];
  const float* wff1  = (const float*)d_in[11];
  const float* bff1  = (const float*)d_in[12];
  const float* wff2  = (const float*)d_in[13];
  const float* bff2  = (const float*)d_in[14];
  float* out = (float*)d_out;
  char*  ws  = (char*)d_ws;

  // ws layout (byte offsets). Peak usage: 121,634,816 bytes = 116 MiB.
  unsigned short* wqkvT = (unsigned short*)(ws);              //  6 MB  [wqT|wkT|wvT] bf16
  unsigned short* woT   = (unsigned short*)(ws +  6291456);   //  2 MB
  unsigned short* wff1T = (unsigned short*)(ws +  8388608);   //  8 MB
  unsigned short* wff2T = (unsigned short*)(ws + 16777216);   //  4 MB
  unsigned short* h     = (unsigned short*)(ws + 20971520);   // 32 MB (ln1/attn_out/ln2, bf16)
  unsigned short* qk    = (unsigned short*)(ws + 54525952);   // 64 MB ([q|k] stride 2048, bf16)
  unsigned short* ff    = qk;                                 // reuses dead qk region (bf16)
  unsigned short* vbuf  = (unsigned short*)d_out;             // V bf16 scratch in d_out (dead until x1)
  float*          x1    = out;                                // x + attn-proj (fp32, in d_out)

  dim3 tb(32, 8);
  transpose_k<<<dim3(32, 32),  tb, 0, stream>>>(wq,   wqkvT,           1024, 1024);
  transpose_k<<<dim3(32, 32),  tb, 0, stream>>>(wk,   wqkvT + 1048576, 1024, 1024);
  transpose_k<<<dim3(32, 32),  tb, 0, stream>>>(wv,   wqkvT + 2097152, 1024, 1024);
  transpose_k<<<dim3(32, 32),  tb, 0, stream>>>(wo,   woT,             1024, 1024);
  transpose_k<<<dim3(128, 32), tb, 0, stream>>>(wff1, wff1T,           1024, 4096);
  transpose_k<<<dim3(32, 64),  tb, 0, stream>>>(wff2, wff2T,           2048, 1024);

  // h = bf16(LN1(x))
  ln_k<<<16384, 256, 0, stream>>>(x, ln1_g, ln1_b, h);
  // [qk | v] = h @ [wq|wk|wv]  (N=3072 fused; cols<2048 -> qk, cols>=2048 -> vbuf in d_out)
  gemm_bt<<<dim3(24, 128), 256, 0, stream>>>(h, wqkvT, qk, vbuf, 3072, 2048, 1024,
                                             nullptr, nullptr, nullptr, 0, 0);
  // attention -> h (bf16 attn_out)
  attn_k<<<dim3(32, 16, 4), 256, 0, stream>>>(qk, vbuf, rel, h);
  // x1 = x + attn_out @ wo + bo   (fp32 into d_out; overwrites dead V)
  gemm_bt<<<dim3(8, 128), 256, 0, stream>>>(h, woT, x1, nullptr, 1024, 1024, 1024,
                                            bo, x, nullptr, 0, 1);
  // h = bf16(LN2(x1))
  ln_k<<<16384, 256, 0, stream>>>(x1, ln2_g, ln2_b, h);
  // ff = gelu(h @ w_ff1[:,2048:] + b_ff1[2048:])          (gate, bf16)
  gemm_bt<<<dim3(16, 128), 256, 0, stream>>>(h, wff1T + 2048*1024, ff, nullptr, 2048, 2048, 1024,
                                             bff1 + 2048, nullptr, nullptr, 1, 0);
  // ff = (h @ w_ff1[:,:2048] + b_ff1[:2048]) * ff         (per-element RMW, bf16)
  gemm_bt<<<dim3(16, 128), 256, 0, stream>>>(h, wff1T, ff, nullptr, 2048, 2048, 1024,
                                             bff1, nullptr, ff, 0, 0);
  // out = x1 + ff @ w_ff2 + b_ff2   (fp32, reads res from d_out, writes d_out; same-thread RMW)
  gemm_bt<<<dim3(8, 128), 256, 0, stream>>>(ff, wff2T, out, nullptr, 1024, 1024, 2048,
                                            bff2, x1, nullptr, 0, 1);
}

// Round 6
// 796.131 us; speedup vs baseline: 1.2546x; 1.1229x over previous
//
#include <hip/hip_runtime.h>
#include <math.h>

typedef __attribute__((ext_vector_type(8))) short s16x8;
typedef __attribute__((ext_vector_type(4))) float f32x4;

__device__ __forceinline__ float b2f(unsigned short u){
  unsigned int i = ((unsigned int)u) << 16;
  float f; __builtin_memcpy(&f, &i, 4); return f;
}
__device__ __forceinline__ unsigned short f2b(float f){
  unsigned int i; __builtin_memcpy(&i, &f, 4);
  unsigned int r = (i + 0x7fffu + ((i >> 16) & 1u)) >> 16;
  return (unsigned short)r;
}
__device__ __forceinline__ f32x4 mfma16(s16x8 a, s16x8 b, f32x4 c){
  return __builtin_amdgcn_mfma_f32_16x16x32_bf16(a, b, c, 0, 0, 0);
}
__device__ __forceinline__ float gelu_exact(float x){
  return 0.5f * x * (1.0f + erff(x * 0.70710678118654752f));
}
// async global->LDS, 16 B per lane; lds base must be wave-uniform (m97 pattern)
__device__ __forceinline__ void gl_lds16(const unsigned short* g, unsigned short* l){
  __builtin_amdgcn_global_load_lds(
      (const __attribute__((address_space(1))) unsigned int*)g,
      (__attribute__((address_space(3))) unsigned int*)l, 16, 0, 0);
}

// ---------------- wave-per-row LayerNorm core (row of 1024, fp32 in, bf16 out) ----------------
__device__ __forceinline__ void ln_row(const float* __restrict__ xrow,
                                       const float* __restrict__ g,
                                       const float* __restrict__ b,
                                       unsigned short* __restrict__ orow, int lane){
  const float4* xr = (const float4*)xrow;
  float4 u[4];
  #pragma unroll
  for(int q = 0; q < 4; q++) u[q] = xr[lane + 64*q];
  float s = 0.0f, ss = 0.0f;
  #pragma unroll
  for(int q = 0; q < 4; q++){
    s  += u[q].x + u[q].y + u[q].z + u[q].w;
    ss += u[q].x*u[q].x + u[q].y*u[q].y + u[q].z*u[q].z + u[q].w*u[q].w;
  }
  #pragma unroll
  for(int o = 32; o; o >>= 1){ s += __shfl_xor(s, o, 64); ss += __shfl_xor(ss, o, 64); }
  float m = s * (1.0f/1024.0f);
  float inv = rsqrtf(ss * (1.0f/1024.0f) - m*m + 1e-5f);
  #pragma unroll
  for(int q = 0; q < 4; q++){
    float4 ug = ((const float4*)g)[lane + 64*q];
    float4 ub = ((const float4*)b)[lane + 64*q];
    ushort4 o4;
    o4.x = f2b((u[q].x - m) * inv * ug.x + ub.x);
    o4.y = f2b((u[q].y - m) * inv * ug.y + ub.y);
    o4.z = f2b((u[q].z - m) * inv * ug.z + ub.z);
    o4.w = f2b((u[q].w - m) * inv * ug.w + ub.w);
    ((ushort4*)orow)[lane + 64*q] = o4;
  }
}

// ---------------- prep: 6 weight transposes (fp32 -> bf16) + LN1, one dispatch ----------------
// blocks [0,10240): transposes; [10240,14336): LN1 (4 rows/block, wave per row)
__global__ __launch_bounds__(256) void prep_k(
    const float* __restrict__ x, const float* __restrict__ ln1_g, const float* __restrict__ ln1_b,
    unsigned short* __restrict__ h,
    const float* __restrict__ wq, const float* __restrict__ wk, const float* __restrict__ wv,
    const float* __restrict__ wo, const float* __restrict__ wff1, const float* __restrict__ wff2,
    unsigned short* __restrict__ wqkvT, unsigned short* __restrict__ woT,
    unsigned short* __restrict__ wff1T, unsigned short* __restrict__ wff2T)
{
  const int bz = blockIdx.x;
  if(bz >= 10240){
    int id = bz - 10240;
    int lane = threadIdx.x & 63, wave = threadIdx.x >> 6;
    int row = id * 4 + wave;
    ln_row(x + (size_t)row*1024, ln1_g, ln1_b, h + (size_t)row*1024, lane);
    return;
  }
  const float* in; unsigned short* out; int R, C, c0, r0;
  if(bz < 4096){
    int w = bz >> 10, id = bz & 1023;       // 4 square 1024x1024 weights
    const float* srcs[4] = {wq, wk, wv, wo};
    unsigned short* dsts[4] = {wqkvT, wqkvT + 1048576, wqkvT + 2097152, woT};
    in = srcs[w]; out = dsts[w]; R = 1024; C = 1024;
    c0 = (id & 31) * 32; r0 = (id >> 5) * 32;
  } else if(bz < 8192){
    int id = bz - 4096;                     // wff1: 1024x4096, grid 128x32
    in = wff1; out = wff1T; R = 1024; C = 4096;
    c0 = (id & 127) * 32; r0 = (id >> 7) * 32;
  } else {
    int id = bz - 8192;                     // wff2: 2048x1024, grid 32x64
    in = wff2; out = wff2T; R = 2048; C = 1024;
    c0 = (id & 31) * 32; r0 = (id >> 5) * 32;
  }
  __shared__ unsigned short tile[32][33];
  int tx = threadIdx.x & 31, ty = threadIdx.x >> 5;   // 32x8
  #pragma unroll
  for(int i = 0; i < 4; i++)
    tile[ty + 8*i][tx] = f2b(in[(size_t)(r0 + ty + 8*i) * C + c0 + tx]);
  __syncthreads();
  #pragma unroll
  for(int i = 0; i < 4; i++)
    out[(size_t)(c0 + ty + 8*i) * R + r0 + tx] = tile[tx][ty + 8*i];
}

// ---------------- standalone LN2 (fp32 in, bf16 out), 4 rows/block ----------------
__global__ __launch_bounds__(256) void ln2_k(const float* __restrict__ x,
                                             const float* __restrict__ g,
                                             const float* __restrict__ b,
                                             unsigned short* __restrict__ out){
  int lane = threadIdx.x & 63, wave = threadIdx.x >> 6;
  int row = blockIdx.x * 4 + wave;
  ln_row(x + (size_t)row*1024, g, b, out + (size_t)row*1024, lane);
}

// ---------------- GEMM: C[M][N] = epi(A[M][K] @ Bt[N][K]^T) ----------------
// 128x128 tile, BK=64, global_load_lds width-16, XOR-swizzled k-groups.
// Output split: cols [0,n_split) -> Cv (stride n_split); cols >= n_split -> Cv2.
__global__ __launch_bounds__(256) void gemm_bt(
    const unsigned short* __restrict__ A, const unsigned short* __restrict__ Bt,
    void* Cv, void* Cv2, int N, int n_split, int K,
    const float* __restrict__ bias, const float* res, int c_fp32)
{
  __shared__ __align__(16) unsigned short As[128 * 64];
  __shared__ __align__(16) unsigned short Bs[128 * 64];

  int m_tile, n_tile;
  {
    unsigned int lin = blockIdx.y * gridDim.x + blockIdx.x;
    unsigned int mt = gridDim.y;
    unsigned int xcd = lin & 7u, idx = lin >> 3, mpx = mt >> 3;
    m_tile = xcd * mpx + (idx % mpx);
    n_tile = idx / mpx;
  }
  const int m0 = m_tile * 128, n0 = n_tile * 128;
  const int tid = threadIdx.x;
  const int wave = tid >> 6, lane = tid & 63;
  const int wm = (wave >> 1) * 64, wn = (wave & 1) * 64;
  const int lrow = lane & 15, quad = lane >> 4;

  const int tr  = tid >> 3;
  const int scg = ((tid & 7) ^ (tr & 7)) * 8;
  const int xw  = lrow & 7;

  f32x4 acc[4][4];
  #pragma unroll
  for(int i = 0; i < 4; i++)
    #pragma unroll
    for(int j = 0; j < 4; j++)
      #pragma unroll
      for(int r = 0; r < 4; r++) acc[i][j][r] = 0.0f;

  const int nk = K >> 6;
  for(int kt = 0; kt < nk; kt++){
    const int k0 = kt << 6;
    if(kt) __syncthreads();
    #pragma unroll
    for(int i = 0; i < 4; i++){
      int row = i*32 + tr;
      gl_lds16(&A [(size_t)(m0 + row)*K + k0 + scg], &As[i*2048 + wave*512]);
      gl_lds16(&Bt[(size_t)(n0 + row)*K + k0 + scg], &Bs[i*2048 + wave*512]);
    }
    __syncthreads();
    #pragma unroll
    for(int kk = 0; kk < 2; kk++){
      s16x8 af[4], bfv[4];
      #pragma unroll
      for(int i = 0; i < 4; i++){
        int ga = ((kk<<2) + quad) ^ xw;
        af [i] = *(const s16x8*)&As[(wm + i*16 + lrow)*64 + ga*8];
        bfv[i] = *(const s16x8*)&Bs[(wn + i*16 + lrow)*64 + ga*8];
      }
      #pragma unroll
      for(int i = 0; i < 4; i++)
        #pragma unroll
        for(int j = 0; j < 4; j++)
          acc[i][j] = mfma16(af[i], bfv[j], acc[i][j]);
    }
  }
  const int qr = quad * 4;
  #pragma unroll
  for(int i = 0; i < 4; i++){
    #pragma unroll
    for(int j = 0; j < 4; j++){
      int col = n0 + wn + j*16 + lrow;
      float bv = bias ? bias[col] : 0.0f;
      #pragma unroll
      for(int r = 0; r < 4; r++){
        int row = m0 + wm + i*16 + qr + r;
        float v = acc[i][j][r] + bv;
        if(col < n_split){
          size_t idx = (size_t)row * n_split + col;
          if(res) v += res[idx];
          if(c_fp32) ((float*)Cv)[idx] = v;
          else       ((unsigned short*)Cv)[idx] = f2b(v);
        } else {
          size_t idx = (size_t)row * (N - n_split) + (col - n_split);
          ((unsigned short*)Cv2)[idx] = f2b(v);
        }
      }
    }
  }
}

// ---------------- fused GEGLU FF1: C[M][2048] = (A@Wv + bv) * gelu(A@Wg + bg) ----------------
// Bt = wff1T [4096][1024]: rows [0,2048) = val cols, [2048,4096) = gate cols.
// Block: 128 rows x 64 val cols (+ matching 64 gate cols). Grid (32, 128).
// Waves wn=0,  wm in {0,64}: val; waves wn=64: gate. Gate passes gelu() through LDS overlay.
__global__ __launch_bounds__(256) void geglu_gemm(
    const unsigned short* __restrict__ A, const unsigned short* __restrict__ Bt,
    unsigned short* __restrict__ C, int K,
    const float* __restrict__ bias)
{
  __shared__ __align__(16) unsigned short pool[2 * 128 * 64];
  unsigned short* As = pool;
  unsigned short* Bs = pool + 128*64;

  int m_tile, n_tile;
  {
    unsigned int lin = blockIdx.y * gridDim.x + blockIdx.x;
    unsigned int mt = gridDim.y;
    unsigned int xcd = lin & 7u, idx = lin >> 3, mpx = mt >> 3;
    m_tile = xcd * mpx + (idx % mpx);
    n_tile = idx / mpx;
  }
  const int m0 = m_tile * 128, nv0 = n_tile * 64;
  const int tid = threadIdx.x;
  const int wave = tid >> 6, lane = tid & 63;
  const int wm = (wave >> 1) * 64, wn = (wave & 1) * 64;
  const int lrow = lane & 15, quad = lane >> 4;

  const int tr  = tid >> 3;
  const int scg = ((tid & 7) ^ (tr & 7)) * 8;
  const int xw  = lrow & 7;

  f32x4 acc[4][4];
  #pragma unroll
  for(int i = 0; i < 4; i++)
    #pragma unroll
    for(int j = 0; j < 4; j++)
      #pragma unroll
      for(int r = 0; r < 4; r++) acc[i][j][r] = 0.0f;

  const int nk = K >> 6;
  for(int kt = 0; kt < nk; kt++){
    const int k0 = kt << 6;
    if(kt) __syncthreads();
    #pragma unroll
    for(int i = 0; i < 4; i++){
      int row = i*32 + tr;                 // Bs row: [0,64) val, [64,128) gate
      int brow = (row < 64) ? (nv0 + row) : (2048 + nv0 + row - 64);
      gl_lds16(&A [(size_t)(m0 + row)*K + k0 + scg], &As[i*2048 + wave*512]);
      gl_lds16(&Bt[(size_t)brow     *K + k0 + scg], &Bs[i*2048 + wave*512]);
    }
    __syncthreads();
    #pragma unroll
    for(int kk = 0; kk < 2; kk++){
      s16x8 af[4], bfv[4];
      #pragma unroll
      for(int i = 0; i < 4; i++){
        int ga = ((kk<<2) + quad) ^ xw;
        af [i] = *(const s16x8*)&As[(wm + i*16 + lrow)*64 + ga*8];
        bfv[i] = *(const s16x8*)&Bs[(wn + i*16 + lrow)*64 + ga*8];
      }
      #pragma unroll
      for(int i = 0; i < 4; i++)
        #pragma unroll
        for(int j = 0; j < 4; j++)
          acc[i][j] = mfma16(af[i], bfv[j], acc[i][j]);
    }
  }
  // epilogue: gate waves -> gelu -> LDS; val waves multiply & store
  __syncthreads();                          // staging pool dead; overlay gS
  float* gS = (float*)pool;                 // [128][64] fp32 = 32 KB
  const int qr = quad * 4;
  if(wn == 64){
    #pragma unroll
    for(int i = 0; i < 4; i++)
      #pragma unroll
      for(int j = 0; j < 4; j++){
        int cl = j*16 + lrow;
        float bv = bias[2048 + nv0 + cl];
        #pragma unroll
        for(int r = 0; r < 4; r++)
          gS[(wm + i*16 + qr + r)*64 + cl] = gelu_exact(acc[i][j][r] + bv);
      }
  }
  __syncthreads();
  if(wn == 0){
    #pragma unroll
    for(int i = 0; i < 4; i++)
      #pragma unroll
      for(int j = 0; j < 4; j++){
        int cl = j*16 + lrow;
        float bv = bias[nv0 + cl];
        #pragma unroll
        for(int r = 0; r < 4; r++){
          int rl = wm + i*16 + qr + r;
          float v = (acc[i][j][r] + bv) * gS[rl*64 + cl];
          C[(size_t)(m0 + rl) * 2048 + nv0 + cl] = f2b(v);
        }
      }
  }
}

// ---------------- sliding-window local attention ----------------
__global__ __launch_bounds__(256, 1) void attn_k(const unsigned short* __restrict__ qk,
                                                 const unsigned short* __restrict__ vbuf,
                                                 const float* __restrict__ rel_bias,
                                                 unsigned short* __restrict__ attn_out)
{
  __shared__ unsigned short kvS[128 * 72];
  __shared__ unsigned short PS[128 * 136];
  __shared__ float biasS[256];

  const int n = blockIdx.x, h = blockIdx.y, b = blockIdx.z;
  const int tid = threadIdx.x;
  const int wave = tid >> 6, lane = tid & 63;
  const int lrow = lane & 15, quad = lane >> 4, lk = quad * 8;
  const int rbase = wave * 32;
  const size_t rowbase = (size_t)b * 4096;
  const int prev = (n > 0) ? (n - 1) : 0;

  biasS[tid] = rel_bias[h * 256 + tid];

  s16x8 aq[2][2];
  #pragma unroll
  for(int mi = 0; mi < 2; mi++)
    #pragma unroll
    for(int kk = 0; kk < 2; kk++)
      aq[mi][kk] = *(const s16x8*)&qk[(rowbase + n*128 + rbase + mi*16 + lrow)*2048
                                      + h*64 + kk*32 + lk];

  f32x4 lg[2][16];
  #pragma unroll
  for(int mi = 0; mi < 2; mi++)
    #pragma unroll
    for(int nj = 0; nj < 16; nj++)
      #pragma unroll
      for(int r = 0; r < 4; r++) lg[mi][nj][r] = 0.0f;

  for(int jh = 0; jh < 2; jh++){
    if(jh) __syncthreads();
    #pragma unroll
    for(int it = 0; it < 4; it++){
      int cid = tid + it * 256;
      int jloc = cid >> 3, c8 = (cid & 7) * 8;
      int j = jh * 128 + jloc;
      int srow = (j < 128) ? (prev*128 + j) : (n*128 + j - 128);
      *(s16x8*)&kvS[jloc*72 + c8] =
        *(const s16x8*)&qk[(rowbase + srow)*2048 + 1024 + h*64 + c8];
    }
    __syncthreads();
    #pragma unroll
    for(int njl = 0; njl < 8; njl++){
      #pragma unroll
      for(int kk = 0; kk < 2; kk++){
        s16x8 bk = *(const s16x8*)&kvS[(njl*16 + lrow)*72 + kk*32 + lk];
        #pragma unroll
        for(int mi = 0; mi < 2; mi++)
          lg[mi][jh*8 + njl] = mfma16(aq[mi][kk], bk, lg[mi][jh*8 + njl]);
      }
    }
  }
  __syncthreads();

  #pragma unroll
  for(int mi = 0; mi < 2; mi++){
    #pragma unroll
    for(int r = 0; r < 4; r++){
      int i = rbase + mi*16 + quad*4 + r;
      float mx = -3e38f;
      #pragma unroll
      for(int nj = 0; nj < 16; nj++){
        int j = nj*16 + lrow;
        int dist = i + 128 - j;
        bool valid = (dist >= 0) && ((n > 0) || (j >= 128));
        float l = valid ? (lg[mi][nj][r] * 0.125f + biasS[dist & 255]) : -1e9f;
        lg[mi][nj][r] = l;
        mx = fmaxf(mx, l);
      }
      #pragma unroll
      for(int o = 1; o < 16; o <<= 1) mx = fmaxf(mx, __shfl_xor(mx, o, 64));
      float s = 0.0f;
      #pragma unroll
      for(int nj = 0; nj < 16; nj++){
        float p = __expf(lg[mi][nj][r] - mx);
        lg[mi][nj][r] = p;
        s += p;
      }
      #pragma unroll
      for(int o = 1; o < 16; o <<= 1) s += __shfl_xor(s, o, 64);
      float inv = 1.0f / s;
      #pragma unroll
      for(int nj = 0; nj < 16; nj++) lg[mi][nj][r] *= inv;
    }
  }

  f32x4 o_acc[2][4];
  #pragma unroll
  for(int mi = 0; mi < 2; mi++)
    #pragma unroll
    for(int nj = 0; nj < 4; nj++)
      #pragma unroll
      for(int r = 0; r < 4; r++) o_acc[mi][nj][r] = 0.0f;

  for(int jh = 0; jh < 2; jh++){
    {
      int jloc = tid >> 1;
      int dbase = (tid & 1) * 32;
      int j = jh * 128 + jloc;
      int srow = (j < 128) ? (prev*128 + j) : (n*128 + j - 128);
      const unsigned short* vr = &vbuf[(rowbase + srow)*1024 + h*64 + dbase];
      #pragma unroll
      for(int i8 = 0; i8 < 4; i8++){
        s16x8 vv = *(const s16x8*)&vr[i8 * 8];
        #pragma unroll
        for(int e = 0; e < 8; e++)
          kvS[(dbase + i8*8 + e)*136 + jloc] = (unsigned short)vv[e];
      }
    }
    #pragma unroll
    for(int mi = 0; mi < 2; mi++)
      #pragma unroll
      for(int r = 0; r < 4; r++)
        #pragma unroll
        for(int njl = 0; njl < 8; njl++)
          PS[(rbase + mi*16 + quad*4 + r)*136 + njl*16 + lrow] = f2b(lg[mi][jh*8 + njl][r]);
    __syncthreads();
    #pragma unroll
    for(int kk = 0; kk < 4; kk++){
      s16x8 ap[2];
      #pragma unroll
      for(int mi = 0; mi < 2; mi++)
        ap[mi] = *(const s16x8*)&PS[(rbase + mi*16 + lrow)*136 + kk*32 + lk];
      #pragma unroll
      for(int nj = 0; nj < 4; nj++){
        s16x8 bv = *(const s16x8*)&kvS[(nj*16 + lrow)*136 + kk*32 + lk];
        #pragma unroll
        for(int mi = 0; mi < 2; mi++)
          o_acc[mi][nj] = mfma16(ap[mi], bv, o_acc[mi][nj]);
      }
    }
    __syncthreads();
  }

  #pragma unroll
  for(int mi = 0; mi < 2; mi++)
    #pragma unroll
    for(int nj = 0; nj < 4; nj++)
      #pragma unroll
      for(int r = 0; r < 4; r++){
        size_t row = rowbase + n*128 + rbase + mi*16 + quad*4 + r;
        int col = h*64 + nj*16 + lrow;
        attn_out[row * 1024 + col] = f2b(o_acc[mi][nj][r]);
      }
}

// ---------------- launcher ----------------
extern "C" void kernel_launch(void* const* d_in, const int* in_sizes, int n_in,
                              void* d_out, int out_size, void* d_ws, size_t ws_size,
                              hipStream_t stream) {
  const float* x     = (const float*)d_in[0];
  const float* ln1_g = (const float*)d_in[1];
  const float* ln1_b = (const float*)d_in[2];
  const float* ln2_g = (const float*)d_in[3];
  const float* ln2_b = (const float*)d_in[4];
  const float* wq    = (const float*)d_in[5];
  const float* wk    = (const float*)d_in[6];
  const float* wv    = (const float*)d_in[7];
  const float* wo    = (const float*)d_in[8];
  const float* bo    = (const float*)d_in[9];
  const float* rel   = (const float*)d_in[10];
  const float* wff1  = (const float*)d_in[11];
  const float* bff1  = (const float*)d_in[12];
  const float* wff2  = (const float*)d_in[13];
  const float* bff2  = (const float*)d_in[14];
  float* out = (float*)d_out;
  char*  ws  = (char*)d_ws;

  // ws layout (byte offsets). Peak usage: 118.6 MiB.
  unsigned short* wqkvT = (unsigned short*)(ws);              //  6 MB
  unsigned short* woT   = (unsigned short*)(ws +  6291456);   //  2 MB
  unsigned short* wff1T = (unsigned short*)(ws +  8388608);   //  8 MB
  unsigned short* wff2T = (unsigned short*)(ws + 16777216);   //  4 MB
  unsigned short* h     = (unsigned short*)(ws + 20971520);   // 32 MB (ln1/attn_out/ln2)
  unsigned short* qk    = (unsigned short*)(ws + 54525952);   // 64 MB ([q|k] stride 2048)
  unsigned short* ff    = qk;                                 // geglu out reuses dead qk
  unsigned short* vbuf  = (unsigned short*)d_out;             // V bf16 scratch (dead until x1)
  float*          x1    = out;                                // fp32, in d_out

  // 1) transposes + LN1
  prep_k<<<14336, 256, 0, stream>>>(x, ln1_g, ln1_b, h,
                                    wq, wk, wv, wo, wff1, wff2,
                                    wqkvT, woT, wff1T, wff2T);
  // 2) [qk | v] = h @ [wq|wk|wv]
  gemm_bt<<<dim3(24, 128), 256, 0, stream>>>(h, wqkvT, qk, vbuf, 3072, 2048, 1024,
                                             nullptr, nullptr, 0);
  // 3) attention -> h
  attn_k<<<dim3(32, 16, 4), 256, 0, stream>>>(qk, vbuf, rel, h);
  // 4) x1 = x + attn_out @ wo + bo  (fp32 into d_out)
  gemm_bt<<<dim3(8, 128), 256, 0, stream>>>(h, woT, x1, nullptr, 1024, 1024, 1024,
                                            bo, x, 1);
  // 5) h = bf16(LN2(x1))
  ln2_k<<<4096, 256, 0, stream>>>(x1, ln2_g, ln2_b, h);
  // 6) ff = (h@Wv + bv) * gelu(h@Wg + bg)   (fused GEGLU)
  geglu_gemm<<<dim3(32, 128), 256, 0, stream>>>(h, wff1T, ff, 1024, bff1);
  // 7) out = x1 + ff @ w_ff2 + b_ff2  (fp32, same-thread RMW on d_out)
  gemm_bt<<<dim3(8, 128), 256, 0, stream>>>(ff, wff2T, out, nullptr, 1024, 1024, 2048,
                                            bff2, x1, 1);
}